// Round 7
// baseline (120.832 us; speedup 1.0000x reference)
//
#include <hip/hip_runtime.h>
#include <hip/hip_bf16.h>

#define HD 768
#define SQ 256
#define NB 4
#define RR 7

typedef short bf16x8 __attribute__((ext_vector_type(8)));
typedef float f32x4  __attribute__((ext_vector_type(4)));

__device__ __forceinline__ float fast_tanh(float x) {
  // tanh(x) = 1 - 2/(e^{2x}+1); stable for large |x|
  float e = __expf(2.0f * x);
  return 1.0f - 2.0f / (e + 1.0f);
}

__device__ __forceinline__ float pair_tanh(float a, float b) {
  // tanh(u+v) = (a+b)/(1+ab) with a=tanh u, b=tanh v (exact identity)
  return (a + b) * __builtin_amdgcn_rcpf(fmaf(a, b, 1.0f));
}

__device__ __forceinline__ short f2bf(float x) {
  return (short)__builtin_bit_cast(unsigned short, __float2bfloat16(x));
}

__device__ __forceinline__ void gl_lds16(const void* g, void* l) {
  // async 16B/lane global->LDS; LDS dest = wave-uniform base + lane*16
  __builtin_amdgcn_global_load_lds(
      (const __attribute__((address_space(1))) void*)g,
      (__attribute__((address_space(3))) void*)l, 16, 0, 0);
}

// ---------------- convert: f32 -> bf16 for X, Wsrc, Wtgt ----------------
__global__ __launch_bounds__(256) void cvt_kernel(
    const float* __restrict__ X, const float* __restrict__ Ws,
    const float* __restrict__ Wt,
    short* __restrict__ Xb, short* __restrict__ Wsb, short* __restrict__ Wtb)
{
  const int NX = NB * SQ * HD / 8;   // 98304 octets
  const int NW = HD * HD / 8;        // 73728 octets
  int i = blockIdx.x * 256 + threadIdx.x;
  const float* src; short* dst;
  if (i < NX)               { src = X;  dst = Xb; }
  else if (i < NX + NW)     { src = Ws; dst = Wsb; i -= NX; }
  else if (i < NX + 2 * NW) { src = Wt; dst = Wtb; i -= NX + NW; }
  else return;
  float4 a = *(const float4*)(src + (size_t)i * 8);
  float4 b = *(const float4*)(src + (size_t)i * 8 + 4);
  bf16x8 r;
  r[0] = f2bf(a.x); r[1] = f2bf(a.y); r[2] = f2bf(a.z); r[3] = f2bf(a.w);
  r[4] = f2bf(b.x); r[5] = f2bf(b.y); r[6] = f2bf(b.z); r[7] = f2bf(b.w);
  *(bf16x8*)(dst + (size_t)i * 8) = r;
}

// -------- Stage 1: ta/tb = tanh(Xb @ Wb^T + bias), pipelined global_load_lds --------
__global__ __launch_bounds__(256) void stage1_lds(
    const short* __restrict__ Xb,
    const short* __restrict__ Wsb, const float* __restrict__ bsrc,
    const short* __restrict__ Wtb, const float* __restrict__ btgt,
    float* __restrict__ ta, float* __restrict__ tb)
{
  constexpr int BK = 64;
  const short* W  = blockIdx.z ? Wtb : Wsb;
  const float* bv = blockIdx.z ? btgt : bsrc;
  float* outp     = blockIdx.z ? tb : ta;
  const int row0 = blockIdx.x * 64, col0 = blockIdx.y * 64;

  // double-buffered; content granule(r,g) = global (r, g^(r&7))
  __shared__ short As[2][64 * BK];
  __shared__ short Bs[2][64 * BK];

  const int tid = threadIdx.x, wave = tid >> 6, lane = tid & 63;
  const int wm = (wave >> 1) * 32, wn = (wave & 1) * 32;

  f32x4 acc[2][2] = {};

  const int G0 = wave * 64 + lane;          // issue-0 granule
  const int r0 = G0 >> 3, g0 = G0 & 7;
  const int G1 = G0 + 256;                  // issue-1 granule
  const int r1 = G1 >> 3, g1 = G1 & 7;

  const size_t xo0 = (size_t)(row0 + r0) * HD + ((g0 ^ (r0 & 7)) * 8);
  const size_t xo1 = (size_t)(row0 + r1) * HD + ((g1 ^ (r1 & 7)) * 8);
  const size_t wo0 = (size_t)(col0 + r0) * HD + ((g0 ^ (r0 & 7)) * 8);
  const size_t wo1 = (size_t)(col0 + r1) * HD + ((g1 ^ (r1 & 7)) * 8);
  short* const la0 = (short*)As + (size_t)(wave * 64) * 8;
  short* const la1 = (short*)As + (size_t)(256 + wave * 64) * 8;
  short* const lb0 = (short*)Bs + (size_t)(wave * 64) * 8;
  short* const lb1 = (short*)Bs + (size_t)(256 + wave * 64) * 8;
  constexpr int BUF = 64 * BK;  // shorts per buffer

  // prologue: stage tile 0 into buf 0
  gl_lds16(Xb + xo0, la0);
  gl_lds16(Xb + xo1, la1);
  gl_lds16(W + wo0, lb0);
  gl_lds16(W + wo1, lb1);

  int cur = 0;
  for (int k0 = 0; k0 < HD; k0 += BK) {
    __syncthreads();   // drains vmcnt(0): buf[cur] ready; prev reads of buf[cur^1] done
    if (k0 + BK < HD) {  // issue next tile into buf[cur^1]; flies under compute
      int nb = (cur ^ 1) * BUF;
      gl_lds16(Xb + xo0 + k0 + BK, la0 + nb);
      gl_lds16(Xb + xo1 + k0 + BK, la1 + nb);
      gl_lds16(W + wo0 + k0 + BK, lb0 + nb);
      gl_lds16(W + wo1 + k0 + BK, lb1 + nb);
    }
    const short* Ac = (const short*)As + cur * BUF;
    const short* Bc = (const short*)Bs + cur * BUF;

    #pragma unroll
    for (int kkb = 0; kkb < 2; ++kkb) {
      bf16x8 af[2], bw[2];
      const int q = kkb * 4 + (lane >> 4);
      #pragma unroll
      for (int i = 0; i < 2; ++i) {
        int ar = wm + i * 16 + (lane & 15);
        af[i] = *(const bf16x8*)&Ac[ar * BK + ((q ^ (ar & 7)) * 8)];
        int br = wn + i * 16 + (lane & 15);
        bw[i] = *(const bf16x8*)&Bc[br * BK + ((q ^ (br & 7)) * 8)];
      }
      #pragma unroll
      for (int i = 0; i < 2; ++i)
        #pragma unroll
        for (int j = 0; j < 2; ++j)
          acc[i][j] = __builtin_amdgcn_mfma_f32_16x16x32_bf16(af[i], bw[j], acc[i][j], 0, 0, 0);
    }
    cur ^= 1;
  }

  #pragma unroll
  for (int j = 0; j < 2; ++j) {
    int n = col0 + wn + j * 16 + (lane & 15);
    float bb = bv[n];
    #pragma unroll
    for (int i = 0; i < 2; ++i)
      #pragma unroll
      for (int r = 0; r < 4; ++r) {
        int m = row0 + wm + i * 16 + (lane >> 4) * 4 + r;
        outp[(size_t)m * HD + n] = fast_tanh(acc[i][j][r] + bb);
      }
  }
}

// -------- Stage 1 fallback (in-kernel convert; used if ws too small) --------
__global__ __launch_bounds__(256) void stage1_mfma(
    const float* __restrict__ X,
    const float* __restrict__ Wsrc, const float* __restrict__ bsrc,
    const float* __restrict__ Wtgt, const float* __restrict__ btgt,
    float* __restrict__ ta, float* __restrict__ tb)
{
  constexpr int BK = 64;
  const float* W  = blockIdx.z ? Wtgt : Wsrc;
  const float* bv = blockIdx.z ? btgt : bsrc;
  float* outp     = blockIdx.z ? tb : ta;
  const int row0 = blockIdx.x * 64, col0 = blockIdx.y * 64;

  __shared__ short As[64 * BK];
  __shared__ short Bs[64 * BK];

  const int tid  = threadIdx.x;
  const int wave = tid >> 6, lane = tid & 63;
  const int wm = (wave >> 1) * 32, wn = (wave & 1) * 32;
  f32x4 acc[2][2] = {};
  const int sr = tid >> 2, sq = tid & 3;

  for (int k0 = 0; k0 < HD; k0 += BK) {
    const float* xa = X + (size_t)(row0 + sr) * HD + k0 + sq * 16;
    const float* xw = W + (size_t)(col0 + sr) * HD + k0 + sq * 16;
    float4 a0 = *(const float4*)(xa + 0), a1 = *(const float4*)(xa + 4);
    float4 a2 = *(const float4*)(xa + 8), a3 = *(const float4*)(xa + 12);
    float4 w0 = *(const float4*)(xw + 0), w1 = *(const float4*)(xw + 4);
    float4 w2 = *(const float4*)(xw + 8), w3 = *(const float4*)(xw + 12);
    __syncthreads();
    bf16x8 p;
    p[0]=f2bf(a0.x);p[1]=f2bf(a0.y);p[2]=f2bf(a0.z);p[3]=f2bf(a0.w);
    p[4]=f2bf(a1.x);p[5]=f2bf(a1.y);p[6]=f2bf(a1.z);p[7]=f2bf(a1.w);
    *(bf16x8*)&As[sr * BK + (((sq * 2 + 0) ^ (sr & 7)) * 8)] = p;
    p[0]=f2bf(a2.x);p[1]=f2bf(a2.y);p[2]=f2bf(a2.z);p[3]=f2bf(a2.w);
    p[4]=f2bf(a3.x);p[5]=f2bf(a3.y);p[6]=f2bf(a3.z);p[7]=f2bf(a3.w);
    *(bf16x8*)&As[sr * BK + (((sq * 2 + 1) ^ (sr & 7)) * 8)] = p;
    p[0]=f2bf(w0.x);p[1]=f2bf(w0.y);p[2]=f2bf(w0.z);p[3]=f2bf(w0.w);
    p[4]=f2bf(w1.x);p[5]=f2bf(w1.y);p[6]=f2bf(w1.z);p[7]=f2bf(w1.w);
    *(bf16x8*)&Bs[sr * BK + (((sq * 2 + 0) ^ (sr & 7)) * 8)] = p;
    p[0]=f2bf(w2.x);p[1]=f2bf(w2.y);p[2]=f2bf(w2.z);p[3]=f2bf(w2.w);
    p[4]=f2bf(w3.x);p[5]=f2bf(w3.y);p[6]=f2bf(w3.z);p[7]=f2bf(w3.w);
    *(bf16x8*)&Bs[sr * BK + (((sq * 2 + 1) ^ (sr & 7)) * 8)] = p;
    __syncthreads();

    #pragma unroll
    for (int kkb = 0; kkb < 2; ++kkb) {
      bf16x8 af[2], bw[2];
      const int q = kkb * 4 + (lane >> 4);
      #pragma unroll
      for (int i = 0; i < 2; ++i) {
        int ar = wm + i * 16 + (lane & 15);
        af[i] = *(const bf16x8*)&As[ar * BK + ((q ^ (ar & 7)) * 8)];
        int br = wn + i * 16 + (lane & 15);
        bw[i] = *(const bf16x8*)&Bs[br * BK + ((q ^ (br & 7)) * 8)];
      }
      #pragma unroll
      for (int i = 0; i < 2; ++i)
        #pragma unroll
        for (int j = 0; j < 2; ++j)
          acc[i][j] = __builtin_amdgcn_mfma_f32_16x16x32_bf16(af[i], bw[j], acc[i][j], 0, 0, 0);
    }
  }

  #pragma unroll
  for (int j = 0; j < 2; ++j) {
    int n = col0 + wn + j * 16 + (lane & 15);
    float bb = bv[n];
    #pragma unroll
    for (int i = 0; i < 2; ++i)
      #pragma unroll
      for (int r = 0; r < 4; ++r) {
        int m = row0 + wm + i * 16 + (lane >> 4) * 4 + r;
        outp[(size_t)m * HD + n] = fast_tanh(acc[i][j][r] + bb);
      }
  }
}

// ---- Stage 2: out[b,s,t,r] via MFMA; each wave owns 4 s-rows, full K ----
__global__ __launch_bounds__(256, 6) void stage2_mfma(
    const float* __restrict__ ta, const float* __restrict__ tb,
    const float* __restrict__ Wout, float* __restrict__ out)
{
  constexpr int HC = 128, LDp = 132;
  const int b  = blockIdx.z;
  const int s0 = blockIdx.y * 16, t0 = blockIdx.x * 16;

  __shared__ float sa[16][LDp];
  __shared__ float sb[16][LDp];

  const int tid = threadIdx.x, wave = tid >> 6, lane = tid & 63;
  const int lg = lane >> 4;       // k sub-group (0..3) / output t-quad
  const int ln = lane & 15;       // A-row t / B-col r

  f32x4 acc[4] = {};              // one per owned s-row, full-K accumulate

  const float* taB = ta + ((size_t)b * SQ + s0) * HD;
  const float* tbB = tb + ((size_t)b * SQ + t0) * HD;

  for (int c = 0; c < HD / HC; ++c) {
    __syncthreads();
    #pragma unroll
    for (int j = 0; j < 2; ++j) {
      int idx = tid + 256 * j, r = idx >> 5, q = idx & 31;
      *(float4*)&sa[r][q * 4] = *(const float4*)(taB + (size_t)r * HD + c * HC + q * 4);
      *(float4*)&sb[r][q * 4] = *(const float4*)(tbB + (size_t)r * HD + c * HC + q * 4);
    }
    __syncthreads();

    #pragma unroll
    for (int m = 0; m < 4; ++m) {
      const int kk = m * 32 + lg * 8;
      // B fragment: B[k][n] = Wout[n][c*HC+kk+j], zero rows n>=7
      bf16x8 bfr;
      float4 u = {0.f, 0.f, 0.f, 0.f}, v = {0.f, 0.f, 0.f, 0.f};
      if (ln < RR) {
        const float* wp = Wout + (size_t)ln * HD + c * HC + kk;
        u = *(const float4*)wp; v = *(const float4*)(wp + 4);
      }
      bfr[0]=f2bf(u.x); bfr[1]=f2bf(u.y); bfr[2]=f2bf(u.z); bfr[3]=f2bf(u.w);
      bfr[4]=f2bf(v.x); bfr[5]=f2bf(v.y); bfr[6]=f2bf(v.z); bfr[7]=f2bf(v.w);
      // tb values for this lane's t row (t = ln)
      float4 q0 = *(const float4*)&sb[ln][kk];
      float4 q1 = *(const float4*)&sb[ln][kk + 4];
      float bvv[8] = {q0.x,q0.y,q0.z,q0.w,q1.x,q1.y,q1.z,q1.w};

      #pragma unroll
      for (int si = 0; si < 4; ++si) {
        const float* ap = &sa[wave * 4 + si][kk];   // broadcast within 16-lane group
        float4 a0 = *(const float4*)ap;
        float4 a1 = *(const float4*)(ap + 4);
        float av[8] = {a0.x,a0.y,a0.z,a0.w,a1.x,a1.y,a1.z,a1.w};
        bf16x8 pa;
        #pragma unroll
        for (int j = 0; j < 8; ++j)
          pa[j] = f2bf(pair_tanh(av[j], bvv[j]));
        acc[si] = __builtin_amdgcn_mfma_f32_16x16x32_bf16(pa, bfr, acc[si], 0, 0, 0);
      }
    }
  }

  // D layout: row(M=t) = lg*4+reg, col(N=r) = ln
  if (ln < RR) {
    #pragma unroll
    for (int si = 0; si < 4; ++si) {
      int s = s0 + wave * 4 + si;
      float* op = out + (((size_t)b * SQ + s) * SQ + t0 + lg * 4) * RR + ln;
      op[0]      = acc[si][0];
      op[RR]     = acc[si][1];
      op[2 * RR] = acc[si][2];
      op[3 * RR] = acc[si][3];
    }
  }
}

extern "C" void kernel_launch(void* const* d_in, const int* in_sizes, int n_in,
                              void* d_out, int out_size, void* d_ws, size_t ws_size,
                              hipStream_t stream) {
  (void)in_sizes; (void)n_in; (void)out_size;
  const float* X    = (const float*)d_in[0];
  const float* Wsrc = (const float*)d_in[1];
  const float* bsrc = (const float*)d_in[2];
  const float* Wtgt = (const float*)d_in[3];
  const float* btgt = (const float*)d_in[4];
  const float* Wout = (const float*)d_in[5];
  float* out = (float*)d_out;

  float* taF = (float*)d_ws;                       // [1024,768] f32
  float* tbF = taF + (size_t)NB * SQ * HD;         // [1024,768] f32
  const size_t base = (size_t)2 * NB * SQ * HD * sizeof(float);
  const size_t need = base + ((size_t)NB * SQ * HD + 2 * (size_t)HD * HD) * sizeof(short);

  if (ws_size >= need) {
    short* Xb  = (short*)((char*)d_ws + base);
    short* Wsb = Xb + (size_t)NB * SQ * HD;
    short* Wtb = Wsb + (size_t)HD * HD;
    cvt_kernel<<<960, 256, 0, stream>>>(X, Wsrc, Wtgt, Xb, Wsb, Wtb);
    stage1_lds<<<dim3(16, 12, 2), 256, 0, stream>>>(Xb, Wsb, bsrc, Wtb, btgt, taF, tbF);
  } else {
    stage1_mfma<<<dim3(16, 12, 2), 256, 0, stream>>>(X, Wsrc, bsrc, Wtgt, btgt, taF, tbF);
  }
  stage2_mfma<<<dim3(SQ / 16, SQ / 16, NB), 256, 0, stream>>>(taF, tbF, Wout, out);
}

// Round 8
// 116.912 us; speedup vs baseline: 1.0335x; 1.0335x over previous
//
#include <hip/hip_runtime.h>
#include <hip/hip_bf16.h>

#define HD 768
#define SQ 256
#define NB 4
#define RR 7

typedef short bf16x8 __attribute__((ext_vector_type(8)));
typedef float f32x4  __attribute__((ext_vector_type(4)));

__device__ __forceinline__ float fast_tanh(float x) {
  // tanh(x) = 1 - 2/(e^{2x}+1); stable for large |x|
  float e = __expf(2.0f * x);
  return 1.0f - 2.0f / (e + 1.0f);
}

__device__ __forceinline__ float pair_tanh(float a, float b) {
  // tanh(u+v) = (a+b)/(1+ab) with a=tanh u, b=tanh v (exact identity)
  return (a + b) * __builtin_amdgcn_rcpf(fmaf(a, b, 1.0f));
}

__device__ __forceinline__ short f2bf(float x) {
  return (short)__builtin_bit_cast(unsigned short, __float2bfloat16(x));
}

__device__ __forceinline__ void gl_lds16(const void* g, void* l) {
  // async 16B/lane global->LDS; LDS dest = wave-uniform base + lane*16
  __builtin_amdgcn_global_load_lds(
      (const __attribute__((address_space(1))) void*)g,
      (__attribute__((address_space(3))) void*)l, 16, 0, 0);
}

// ---------------- convert: f32 -> bf16 for X, Wsrc, Wtgt, Wout ----------------
__global__ __launch_bounds__(256) void cvt_kernel(
    const float* __restrict__ X, const float* __restrict__ Ws,
    const float* __restrict__ Wt, const float* __restrict__ Wo,
    short* __restrict__ Xb, short* __restrict__ Wsb,
    short* __restrict__ Wtb, short* __restrict__ Wob)
{
  const int NX = NB * SQ * HD / 8;   // 98304 octets
  const int NW = HD * HD / 8;        // 73728 octets
  const int NO = RR * HD / 8;        // 672 octets
  int i = blockIdx.x * 256 + threadIdx.x;
  const float* src; short* dst;
  if (i < NX)                    { src = X;  dst = Xb; }
  else if (i < NX + NW)          { src = Ws; dst = Wsb; i -= NX; }
  else if (i < NX + 2 * NW)      { src = Wt; dst = Wtb; i -= NX + NW; }
  else if (i < NX + 2 * NW + NO) { src = Wo; dst = Wob; i -= NX + 2 * NW; }
  else return;
  float4 a = *(const float4*)(src + (size_t)i * 8);
  float4 b = *(const float4*)(src + (size_t)i * 8 + 4);
  bf16x8 r;
  r[0] = f2bf(a.x); r[1] = f2bf(a.y); r[2] = f2bf(a.z); r[3] = f2bf(a.w);
  r[4] = f2bf(b.x); r[5] = f2bf(b.y); r[6] = f2bf(b.z); r[7] = f2bf(b.w);
  *(bf16x8*)(dst + (size_t)i * 8) = r;
}

// small fallback converter: Wout only
__global__ __launch_bounds__(256) void cvt_wout(
    const float* __restrict__ Wo, short* __restrict__ Wob)
{
  const int NO = RR * HD / 8;
  int i = blockIdx.x * 256 + threadIdx.x;
  if (i >= NO) return;
  float4 a = *(const float4*)(Wo + (size_t)i * 8);
  float4 b = *(const float4*)(Wo + (size_t)i * 8 + 4);
  bf16x8 r;
  r[0] = f2bf(a.x); r[1] = f2bf(a.y); r[2] = f2bf(a.z); r[3] = f2bf(a.w);
  r[4] = f2bf(b.x); r[5] = f2bf(b.y); r[6] = f2bf(b.z); r[7] = f2bf(b.w);
  *(bf16x8*)(Wob + (size_t)i * 8) = r;
}

// -------- Stage 1: ta/tb = tanh(Xb @ Wb^T + bias), pipelined global_load_lds --------
__global__ __launch_bounds__(256) void stage1_lds(
    const short* __restrict__ Xb,
    const short* __restrict__ Wsb, const float* __restrict__ bsrc,
    const short* __restrict__ Wtb, const float* __restrict__ btgt,
    float* __restrict__ ta, float* __restrict__ tb)
{
  constexpr int BK = 64;
  const short* W  = blockIdx.z ? Wtb : Wsb;
  const float* bv = blockIdx.z ? btgt : bsrc;
  float* outp     = blockIdx.z ? tb : ta;
  const int row0 = blockIdx.x * 64, col0 = blockIdx.y * 64;

  // double-buffered; content granule(r,g) = global (r, g^(r&7))
  __shared__ short As[2][64 * BK];
  __shared__ short Bs[2][64 * BK];

  const int tid = threadIdx.x, wave = tid >> 6, lane = tid & 63;
  const int wm = (wave >> 1) * 32, wn = (wave & 1) * 32;

  f32x4 acc[2][2] = {};

  const int G0 = wave * 64 + lane;          // issue-0 granule
  const int r0 = G0 >> 3, g0 = G0 & 7;
  const int G1 = G0 + 256;                  // issue-1 granule
  const int r1 = G1 >> 3, g1 = G1 & 7;

  const size_t xo0 = (size_t)(row0 + r0) * HD + ((g0 ^ (r0 & 7)) * 8);
  const size_t xo1 = (size_t)(row0 + r1) * HD + ((g1 ^ (r1 & 7)) * 8);
  const size_t wo0 = (size_t)(col0 + r0) * HD + ((g0 ^ (r0 & 7)) * 8);
  const size_t wo1 = (size_t)(col0 + r1) * HD + ((g1 ^ (r1 & 7)) * 8);
  short* const la0 = (short*)As + (size_t)(wave * 64) * 8;
  short* const la1 = (short*)As + (size_t)(256 + wave * 64) * 8;
  short* const lb0 = (short*)Bs + (size_t)(wave * 64) * 8;
  short* const lb1 = (short*)Bs + (size_t)(256 + wave * 64) * 8;
  constexpr int BUF = 64 * BK;  // shorts per buffer

  // prologue: stage tile 0 into buf 0
  gl_lds16(Xb + xo0, la0);
  gl_lds16(Xb + xo1, la1);
  gl_lds16(W + wo0, lb0);
  gl_lds16(W + wo1, lb1);

  int cur = 0;
  for (int k0 = 0; k0 < HD; k0 += BK) {
    __syncthreads();   // drains vmcnt(0): buf[cur] ready; prev reads of buf[cur^1] done
    if (k0 + BK < HD) {  // issue next tile into buf[cur^1]; flies under compute
      int nb = (cur ^ 1) * BUF;
      gl_lds16(Xb + xo0 + k0 + BK, la0 + nb);
      gl_lds16(Xb + xo1 + k0 + BK, la1 + nb);
      gl_lds16(W + wo0 + k0 + BK, lb0 + nb);
      gl_lds16(W + wo1 + k0 + BK, lb1 + nb);
    }
    const short* Ac = (const short*)As + cur * BUF;
    const short* Bc = (const short*)Bs + cur * BUF;

    #pragma unroll
    for (int kkb = 0; kkb < 2; ++kkb) {
      bf16x8 af[2], bw[2];
      const int q = kkb * 4 + (lane >> 4);
      #pragma unroll
      for (int i = 0; i < 2; ++i) {
        int ar = wm + i * 16 + (lane & 15);
        af[i] = *(const bf16x8*)&Ac[ar * BK + ((q ^ (ar & 7)) * 8)];
        int br = wn + i * 16 + (lane & 15);
        bw[i] = *(const bf16x8*)&Bc[br * BK + ((q ^ (br & 7)) * 8)];
      }
      #pragma unroll
      for (int i = 0; i < 2; ++i)
        #pragma unroll
        for (int j = 0; j < 2; ++j)
          acc[i][j] = __builtin_amdgcn_mfma_f32_16x16x32_bf16(af[i], bw[j], acc[i][j], 0, 0, 0);
    }
    cur ^= 1;
  }

  #pragma unroll
  for (int j = 0; j < 2; ++j) {
    int n = col0 + wn + j * 16 + (lane & 15);
    float bb = bv[n];
    #pragma unroll
    for (int i = 0; i < 2; ++i)
      #pragma unroll
      for (int r = 0; r < 4; ++r) {
        int m = row0 + wm + i * 16 + (lane >> 4) * 4 + r;
        outp[(size_t)m * HD + n] = fast_tanh(acc[i][j][r] + bb);
      }
  }
}

// -------- Stage 1 fallback (in-kernel convert; used if ws too small) --------
__global__ __launch_bounds__(256) void stage1_mfma(
    const float* __restrict__ X,
    const float* __restrict__ Wsrc, const float* __restrict__ bsrc,
    const float* __restrict__ Wtgt, const float* __restrict__ btgt,
    float* __restrict__ ta, float* __restrict__ tb)
{
  constexpr int BK = 64;
  const float* W  = blockIdx.z ? Wtgt : Wsrc;
  const float* bv = blockIdx.z ? btgt : bsrc;
  float* outp     = blockIdx.z ? tb : ta;
  const int row0 = blockIdx.x * 64, col0 = blockIdx.y * 64;

  __shared__ short As[64 * BK];
  __shared__ short Bs[64 * BK];

  const int tid  = threadIdx.x;
  const int wave = tid >> 6, lane = tid & 63;
  const int wm = (wave >> 1) * 32, wn = (wave & 1) * 32;
  f32x4 acc[2][2] = {};
  const int sr = tid >> 2, sq = tid & 3;

  for (int k0 = 0; k0 < HD; k0 += BK) {
    const float* xa = X + (size_t)(row0 + sr) * HD + k0 + sq * 16;
    const float* xw = W + (size_t)(col0 + sr) * HD + k0 + sq * 16;
    float4 a0 = *(const float4*)(xa + 0), a1 = *(const float4*)(xa + 4);
    float4 a2 = *(const float4*)(xa + 8), a3 = *(const float4*)(xa + 12);
    float4 w0 = *(const float4*)(xw + 0), w1 = *(const float4*)(xw + 4);
    float4 w2 = *(const float4*)(xw + 8), w3 = *(const float4*)(xw + 12);
    __syncthreads();
    bf16x8 p;
    p[0]=f2bf(a0.x);p[1]=f2bf(a0.y);p[2]=f2bf(a0.z);p[3]=f2bf(a0.w);
    p[4]=f2bf(a1.x);p[5]=f2bf(a1.y);p[6]=f2bf(a1.z);p[7]=f2bf(a1.w);
    *(bf16x8*)&As[sr * BK + (((sq * 2 + 0) ^ (sr & 7)) * 8)] = p;
    p[0]=f2bf(a2.x);p[1]=f2bf(a2.y);p[2]=f2bf(a2.z);p[3]=f2bf(a2.w);
    p[4]=f2bf(a3.x);p[5]=f2bf(a3.y);p[6]=f2bf(a3.z);p[7]=f2bf(a3.w);
    *(bf16x8*)&As[sr * BK + (((sq * 2 + 1) ^ (sr & 7)) * 8)] = p;
    p[0]=f2bf(w0.x);p[1]=f2bf(w0.y);p[2]=f2bf(w0.z);p[3]=f2bf(w0.w);
    p[4]=f2bf(w1.x);p[5]=f2bf(w1.y);p[6]=f2bf(w1.z);p[7]=f2bf(w1.w);
    *(bf16x8*)&Bs[sr * BK + (((sq * 2 + 0) ^ (sr & 7)) * 8)] = p;
    p[0]=f2bf(w2.x);p[1]=f2bf(w2.y);p[2]=f2bf(w2.z);p[3]=f2bf(w2.w);
    p[4]=f2bf(w3.x);p[5]=f2bf(w3.y);p[6]=f2bf(w3.z);p[7]=f2bf(w3.w);
    *(bf16x8*)&Bs[sr * BK + (((sq * 2 + 1) ^ (sr & 7)) * 8)] = p;
    __syncthreads();

    #pragma unroll
    for (int kkb = 0; kkb < 2; ++kkb) {
      bf16x8 af[2], bw[2];
      const int q = kkb * 4 + (lane >> 4);
      #pragma unroll
      for (int i = 0; i < 2; ++i) {
        int ar = wm + i * 16 + (lane & 15);
        af[i] = *(const bf16x8*)&As[ar * BK + ((q ^ (ar & 7)) * 8)];
        int br = wn + i * 16 + (lane & 15);
        bw[i] = *(const bf16x8*)&Bs[br * BK + ((q ^ (br & 7)) * 8)];
      }
      #pragma unroll
      for (int i = 0; i < 2; ++i)
        #pragma unroll
        for (int j = 0; j < 2; ++j)
          acc[i][j] = __builtin_amdgcn_mfma_f32_16x16x32_bf16(af[i], bw[j], acc[i][j], 0, 0, 0);
    }
  }

  #pragma unroll
  for (int j = 0; j < 2; ++j) {
    int n = col0 + wn + j * 16 + (lane & 15);
    float bb = bv[n];
    #pragma unroll
    for (int i = 0; i < 2; ++i)
      #pragma unroll
      for (int r = 0; r < 4; ++r) {
        int m = row0 + wm + i * 16 + (lane >> 4) * 4 + r;
        outp[(size_t)m * HD + n] = fast_tanh(acc[i][j][r] + bb);
      }
  }
}

// ---- Stage 2: out[b,s,t,r] via MFMA; 8s x 16t tile, wave owns 2 s-rows, full K ----
__global__ __launch_bounds__(256, 8) void stage2_mfma(
    const float* __restrict__ ta, const float* __restrict__ tb,
    const short* __restrict__ Woutb, float* __restrict__ out)
{
  constexpr int HC = 128, LDp = 132;
  const int b  = blockIdx.z;
  const int s0 = blockIdx.y * 8, t0 = blockIdx.x * 16;

  __shared__ float sa[8][LDp];
  __shared__ float sb[16][LDp];

  const int tid = threadIdx.x, wave = tid >> 6, lane = tid & 63;
  const int lg = lane >> 4;       // k sub-group (0..3) / output t-quad
  const int ln = lane & 15;       // A-row t / B-col r

  f32x4 acc[2] = {};              // one per owned s-row, full-K accumulate

  const float* taB = ta + ((size_t)b * SQ + s0) * HD;
  const float* tbB = tb + ((size_t)b * SQ + t0) * HD;

  for (int c = 0; c < HD / HC; ++c) {
    __syncthreads();
    { int r = tid >> 5, q = tid & 31;   // 8*32 float4 = 256
      *(float4*)&sa[r][q * 4] = *(const float4*)(taB + (size_t)r * HD + c * HC + q * 4); }
    #pragma unroll
    for (int j = 0; j < 2; ++j) {       // 16*32 float4 = 512
      int idx = tid + 256 * j, r = idx >> 5, q = idx & 31;
      *(float4*)&sb[r][q * 4] = *(const float4*)(tbB + (size_t)r * HD + c * HC + q * 4);
    }
    __syncthreads();

    #pragma unroll
    for (int m = 0; m < 4; ++m) {
      const int kk = m * 32 + lg * 8;
      // B fragment: B[k][n] = Wout[n][c*HC+kk+j] (bf16, pre-converted), zero n>=7
      bf16x8 bfr = {};
      if (ln < RR)
        bfr = *(const bf16x8*)(Woutb + (size_t)ln * HD + c * HC + kk);
      // tb values for this lane's t row (t = ln)
      float4 q0 = *(const float4*)&sb[ln][kk];
      float4 q1 = *(const float4*)&sb[ln][kk + 4];
      float bvv[8] = {q0.x,q0.y,q0.z,q0.w,q1.x,q1.y,q1.z,q1.w};

      #pragma unroll
      for (int si = 0; si < 2; ++si) {
        const float* ap = &sa[wave * 2 + si][kk];   // broadcast within 16-lane group
        float4 a0 = *(const float4*)ap;
        float4 a1 = *(const float4*)(ap + 4);
        float av[8] = {a0.x,a0.y,a0.z,a0.w,a1.x,a1.y,a1.z,a1.w};
        bf16x8 pa;
        #pragma unroll
        for (int j = 0; j < 8; ++j)
          pa[j] = f2bf(pair_tanh(av[j], bvv[j]));
        acc[si] = __builtin_amdgcn_mfma_f32_16x16x32_bf16(pa, bfr, acc[si], 0, 0, 0);
      }
    }
  }

  // D layout: row(M=t) = lg*4+reg, col(N=r) = ln
  if (ln < RR) {
    #pragma unroll
    for (int si = 0; si < 2; ++si) {
      int s = s0 + wave * 2 + si;
      float* op = out + (((size_t)b * SQ + s) * SQ + t0 + lg * 4) * RR + ln;
      op[0]      = acc[si][0];
      op[RR]     = acc[si][1];
      op[2 * RR] = acc[si][2];
      op[3 * RR] = acc[si][3];
    }
  }
}

extern "C" void kernel_launch(void* const* d_in, const int* in_sizes, int n_in,
                              void* d_out, int out_size, void* d_ws, size_t ws_size,
                              hipStream_t stream) {
  (void)in_sizes; (void)n_in; (void)out_size;
  const float* X    = (const float*)d_in[0];
  const float* Wsrc = (const float*)d_in[1];
  const float* bsrc = (const float*)d_in[2];
  const float* Wtgt = (const float*)d_in[3];
  const float* btgt = (const float*)d_in[4];
  const float* Wout = (const float*)d_in[5];
  float* out = (float*)d_out;

  float* taF = (float*)d_ws;                       // [1024,768] f32
  float* tbF = taF + (size_t)NB * SQ * HD;         // [1024,768] f32
  const size_t base = (size_t)2 * NB * SQ * HD * sizeof(float);
  short* Xb  = (short*)((char*)d_ws + base);
  short* Wsb = Xb + (size_t)NB * SQ * HD;
  short* Wtb = Wsb + (size_t)HD * HD;
  short* Wob = Wtb + (size_t)HD * HD;
  const size_t need = base +
      ((size_t)NB * SQ * HD + 2 * (size_t)HD * HD + (size_t)RR * HD) * sizeof(short);

  const short* WobUse;
  if (ws_size >= need) {
    cvt_kernel<<<963, 256, 0, stream>>>(X, Wsrc, Wtgt, Wout, Xb, Wsb, Wtb, Wob);
    stage1_lds<<<dim3(16, 12, 2), 256, 0, stream>>>(Xb, Wsb, bsrc, Wtb, btgt, taF, tbF);
    WobUse = Wob;
  } else {
    short* WobF = (short*)((char*)d_ws + base);   // only Wout bf16 after ta/tb
    cvt_wout<<<3, 256, 0, stream>>>(Wout, WobF);
    stage1_mfma<<<dim3(16, 12, 2), 256, 0, stream>>>(X, Wsrc, bsrc, Wtgt, btgt, taF, tbF);
    WobUse = WobF;
  }
  stage2_mfma<<<dim3(SQ / 16, SQ / 8, NB), 256, 0, stream>>>(taF, tbF, WobUse, out);
}

// Round 10
// 114.955 us; speedup vs baseline: 1.0511x; 1.0170x over previous
//
#include <hip/hip_runtime.h>
#include <hip/hip_bf16.h>

#define HD 768
#define SQ 256
#define NB 4
#define RR 7

typedef short bf16x8 __attribute__((ext_vector_type(8)));
typedef float f32x4  __attribute__((ext_vector_type(4)));

__device__ __forceinline__ float fast_tanh(float x) {
  // tanh(x) = 1 - 2/(e^{2x}+1); stable for large |x|
  float e = __expf(2.0f * x);
  return 1.0f - 2.0f / (e + 1.0f);
}

__device__ __forceinline__ float pair_tanh(float a, float b) {
  // tanh(u+v) = (a+b)/(1+ab) with a=tanh u, b=tanh v (exact identity)
  return (a + b) * __builtin_amdgcn_rcpf(fmaf(a, b, 1.0f));
}

__device__ __forceinline__ short f2bf(float x) {
  return (short)__builtin_bit_cast(unsigned short, __float2bfloat16(x));
}

__device__ __forceinline__ void gl_lds16(const void* g, void* l) {
  // async 16B/lane global->LDS; LDS dest = wave-uniform base + lane*16
  __builtin_amdgcn_global_load_lds(
      (const __attribute__((address_space(1))) void*)g,
      (__attribute__((address_space(3))) void*)l, 16, 0, 0);
}

// ------- convert: f32 -> bf16 for X, Wsrc, Wtgt; Wout padded to 16 rows -------
__global__ __launch_bounds__(256) void cvt_kernel(
    const float* __restrict__ X, const float* __restrict__ Ws,
    const float* __restrict__ Wt, const float* __restrict__ Wo,
    short* __restrict__ Xb, short* __restrict__ Wsb,
    short* __restrict__ Wtb, short* __restrict__ Wob)
{
  const int NX = NB * SQ * HD / 8;   // 98304 octets
  const int NW = HD * HD / 8;        // 73728 octets
  const int NO = 16 * HD / 8;        // 1536 octets (padded rows)
  int i = blockIdx.x * 256 + threadIdx.x;
  const float* src; short* dst;
  if (i < NX)               { src = X;  dst = Xb; }
  else if (i < NX + NW)     { src = Ws; dst = Wsb; i -= NX; }
  else if (i < NX + 2 * NW) { src = Wt; dst = Wtb; i -= NX + NW; }
  else if (i < NX + 2 * NW + NO) {
    i -= NX + 2 * NW;
    int row = i / (HD / 8);
    bf16x8 r = {};
    if (row < RR) {
      float4 a = *(const float4*)(Wo + (size_t)i * 8);
      float4 b = *(const float4*)(Wo + (size_t)i * 8 + 4);
      r[0] = f2bf(a.x); r[1] = f2bf(a.y); r[2] = f2bf(a.z); r[3] = f2bf(a.w);
      r[4] = f2bf(b.x); r[5] = f2bf(b.y); r[6] = f2bf(b.z); r[7] = f2bf(b.w);
    }
    *(bf16x8*)(Wob + (size_t)i * 8) = r;
    return;
  } else return;
  float4 a = *(const float4*)(src + (size_t)i * 8);
  float4 b = *(const float4*)(src + (size_t)i * 8 + 4);
  bf16x8 r;
  r[0] = f2bf(a.x); r[1] = f2bf(a.y); r[2] = f2bf(a.z); r[3] = f2bf(a.w);
  r[4] = f2bf(b.x); r[5] = f2bf(b.y); r[6] = f2bf(b.z); r[7] = f2bf(b.w);
  *(bf16x8*)(dst + (size_t)i * 8) = r;
}

// small fallback converter: Wout only (padded to 16 rows)
__global__ __launch_bounds__(256) void cvt_wout(
    const float* __restrict__ Wo, short* __restrict__ Wob)
{
  const int NO = 16 * HD / 8;
  int i = blockIdx.x * 256 + threadIdx.x;
  if (i >= NO) return;
  int row = i / (HD / 8);
  bf16x8 r = {};
  if (row < RR) {
    float4 a = *(const float4*)(Wo + (size_t)i * 8);
    float4 b = *(const float4*)(Wo + (size_t)i * 8 + 4);
    r[0] = f2bf(a.x); r[1] = f2bf(a.y); r[2] = f2bf(a.z); r[3] = f2bf(a.w);
    r[4] = f2bf(b.x); r[5] = f2bf(b.y); r[6] = f2bf(b.z); r[7] = f2bf(b.w);
  }
  *(bf16x8*)(Wob + (size_t)i * 8) = r;
}

// -------- Stage 1: ta/tb = tanh(Xb @ Wb^T + bias), pipelined global_load_lds --------
__global__ __launch_bounds__(256) void stage1_lds(
    const short* __restrict__ Xb,
    const short* __restrict__ Wsb, const float* __restrict__ bsrc,
    const short* __restrict__ Wtb, const float* __restrict__ btgt,
    float* __restrict__ ta, float* __restrict__ tb)
{
  constexpr int BK = 64;
  const short* W  = blockIdx.z ? Wtb : Wsb;
  const float* bv = blockIdx.z ? btgt : bsrc;
  float* outp     = blockIdx.z ? tb : ta;
  const int row0 = blockIdx.x * 64, col0 = blockIdx.y * 64;

  // double-buffered; content granule(r,g) = global (r, g^(r&7))
  __shared__ short As[2][64 * BK];
  __shared__ short Bs[2][64 * BK];

  const int tid = threadIdx.x, wave = tid >> 6, lane = tid & 63;
  const int wm = (wave >> 1) * 32, wn = (wave & 1) * 32;

  f32x4 acc[2][2] = {};

  const int G0 = wave * 64 + lane;          // issue-0 granule
  const int r0 = G0 >> 3, g0 = G0 & 7;
  const int G1 = G0 + 256;                  // issue-1 granule
  const int r1 = G1 >> 3, g1 = G1 & 7;

  const size_t xo0 = (size_t)(row0 + r0) * HD + ((g0 ^ (r0 & 7)) * 8);
  const size_t xo1 = (size_t)(row0 + r1) * HD + ((g1 ^ (r1 & 7)) * 8);
  const size_t wo0 = (size_t)(col0 + r0) * HD + ((g0 ^ (r0 & 7)) * 8);
  const size_t wo1 = (size_t)(col0 + r1) * HD + ((g1 ^ (r1 & 7)) * 8);
  short* const la0 = (short*)As + (size_t)(wave * 64) * 8;
  short* const la1 = (short*)As + (size_t)(256 + wave * 64) * 8;
  short* const lb0 = (short*)Bs + (size_t)(wave * 64) * 8;
  short* const lb1 = (short*)Bs + (size_t)(256 + wave * 64) * 8;
  constexpr int BUF = 64 * BK;  // shorts per buffer

  // prologue: stage tile 0 into buf 0
  gl_lds16(Xb + xo0, la0);
  gl_lds16(Xb + xo1, la1);
  gl_lds16(W + wo0, lb0);
  gl_lds16(W + wo1, lb1);

  int cur = 0;
  for (int k0 = 0; k0 < HD; k0 += BK) {
    __syncthreads();   // drains vmcnt(0): buf[cur] ready; prev reads of buf[cur^1] done
    if (k0 + BK < HD) {  // issue next tile into buf[cur^1]; flies under compute
      int nb = (cur ^ 1) * BUF;
      gl_lds16(Xb + xo0 + k0 + BK, la0 + nb);
      gl_lds16(Xb + xo1 + k0 + BK, la1 + nb);
      gl_lds16(W + wo0 + k0 + BK, lb0 + nb);
      gl_lds16(W + wo1 + k0 + BK, lb1 + nb);
    }
    const short* Ac = (const short*)As + cur * BUF;
    const short* Bc = (const short*)Bs + cur * BUF;

    #pragma unroll
    for (int kkb = 0; kkb < 2; ++kkb) {
      bf16x8 af[2], bw[2];
      const int q = kkb * 4 + (lane >> 4);
      #pragma unroll
      for (int i = 0; i < 2; ++i) {
        int ar = wm + i * 16 + (lane & 15);
        af[i] = *(const bf16x8*)&Ac[ar * BK + ((q ^ (ar & 7)) * 8)];
        int br = wn + i * 16 + (lane & 15);
        bw[i] = *(const bf16x8*)&Bc[br * BK + ((q ^ (br & 7)) * 8)];
      }
      #pragma unroll
      for (int i = 0; i < 2; ++i)
        #pragma unroll
        for (int j = 0; j < 2; ++j)
          acc[i][j] = __builtin_amdgcn_mfma_f32_16x16x32_bf16(af[i], bw[j], acc[i][j], 0, 0, 0);
    }
    cur ^= 1;
  }

  #pragma unroll
  for (int j = 0; j < 2; ++j) {
    int n = col0 + wn + j * 16 + (lane & 15);
    float bb = bv[n];
    #pragma unroll
    for (int i = 0; i < 2; ++i)
      #pragma unroll
      for (int r = 0; r < 4; ++r) {
        int m = row0 + wm + i * 16 + (lane >> 4) * 4 + r;
        outp[(size_t)m * HD + n] = fast_tanh(acc[i][j][r] + bb);
      }
  }
}

// -------- Stage 1 fallback (in-kernel convert; used if ws too small) --------
__global__ __launch_bounds__(256) void stage1_mfma(
    const float* __restrict__ X,
    const float* __restrict__ Wsrc, const float* __restrict__ bsrc,
    const float* __restrict__ Wtgt, const float* __restrict__ btgt,
    float* __restrict__ ta, float* __restrict__ tb)
{
  constexpr int BK = 64;
  const float* W  = blockIdx.z ? Wtgt : Wsrc;
  const float* bv = blockIdx.z ? btgt : bsrc;
  float* outp     = blockIdx.z ? tb : ta;
  const int row0 = blockIdx.x * 64, col0 = blockIdx.y * 64;

  __shared__ short As[64 * BK];
  __shared__ short Bs[64 * BK];

  const int tid  = threadIdx.x;
  const int wave = tid >> 6, lane = tid & 63;
  const int wm = (wave >> 1) * 32, wn = (wave & 1) * 32;
  f32x4 acc[2][2] = {};
  const int sr = tid >> 2, sq = tid & 3;

  for (int k0 = 0; k0 < HD; k0 += BK) {
    const float* xa = X + (size_t)(row0 + sr) * HD + k0 + sq * 16;
    const float* xw = W + (size_t)(col0 + sr) * HD + k0 + sq * 16;
    float4 a0 = *(const float4*)(xa + 0), a1 = *(const float4*)(xa + 4);
    float4 a2 = *(const float4*)(xa + 8), a3 = *(const float4*)(xa + 12);
    float4 w0 = *(const float4*)(xw + 0), w1 = *(const float4*)(xw + 4);
    float4 w2 = *(const float4*)(xw + 8), w3 = *(const float4*)(xw + 12);
    __syncthreads();
    bf16x8 p;
    p[0]=f2bf(a0.x);p[1]=f2bf(a0.y);p[2]=f2bf(a0.z);p[3]=f2bf(a0.w);
    p[4]=f2bf(a1.x);p[5]=f2bf(a1.y);p[6]=f2bf(a1.z);p[7]=f2bf(a1.w);
    *(bf16x8*)&As[sr * BK + (((sq * 2 + 0) ^ (sr & 7)) * 8)] = p;
    p[0]=f2bf(a2.x);p[1]=f2bf(a2.y);p[2]=f2bf(a2.z);p[3]=f2bf(a2.w);
    p[4]=f2bf(a3.x);p[5]=f2bf(a3.y);p[6]=f2bf(a3.z);p[7]=f2bf(a3.w);
    *(bf16x8*)&As[sr * BK + (((sq * 2 + 1) ^ (sr & 7)) * 8)] = p;
    p[0]=f2bf(w0.x);p[1]=f2bf(w0.y);p[2]=f2bf(w0.z);p[3]=f2bf(w0.w);
    p[4]=f2bf(w1.x);p[5]=f2bf(w1.y);p[6]=f2bf(w1.z);p[7]=f2bf(w1.w);
    *(bf16x8*)&Bs[sr * BK + (((sq * 2 + 0) ^ (sr & 7)) * 8)] = p;
    p[0]=f2bf(w2.x);p[1]=f2bf(w2.y);p[2]=f2bf(w2.z);p[3]=f2bf(w2.w);
    p[4]=f2bf(w3.x);p[5]=f2bf(w3.y);p[6]=f2bf(w3.z);p[7]=f2bf(w3.w);
    *(bf16x8*)&Bs[sr * BK + (((sq * 2 + 1) ^ (sr & 7)) * 8)] = p;
    __syncthreads();

    #pragma unroll
    for (int kkb = 0; kkb < 2; ++kkb) {
      bf16x8 af[2], bw[2];
      const int q = kkb * 4 + (lane >> 4);
      #pragma unroll
      for (int i = 0; i < 2; ++i) {
        int ar = wm + i * 16 + (lane & 15);
        af[i] = *(const bf16x8*)&As[ar * BK + ((q ^ (ar & 7)) * 8)];
        int br = wn + i * 16 + (lane & 15);
        bw[i] = *(const bf16x8*)&Bs[br * BK + ((q ^ (br & 7)) * 8)];
      }
      #pragma unroll
      for (int i = 0; i < 2; ++i)
        #pragma unroll
        for (int j = 0; j < 2; ++j)
          acc[i][j] = __builtin_amdgcn_mfma_f32_16x16x32_bf16(af[i], bw[j], acc[i][j], 0, 0, 0);
    }
  }

  #pragma unroll
  for (int j = 0; j < 2; ++j) {
    int n = col0 + wn + j * 16 + (lane & 15);
    float bb = bv[n];
    #pragma unroll
    for (int i = 0; i < 2; ++i)
      #pragma unroll
      for (int r = 0; r < 4; ++r) {
        int m = row0 + wm + i * 16 + (lane >> 4) * 4 + r;
        outp[(size_t)m * HD + n] = fast_tanh(acc[i][j][r] + bb);
      }
  }
}

// ---- Stage 2: out[b,s,t,r] via MFMA; 8s x 16t tile, wave owns 2 s-rows.
//      Split staging: prefetch chunk c+1 to regs under chunk c's compute. ----
__global__ __launch_bounds__(256, 6) void stage2_mfma(
    const float* __restrict__ ta, const float* __restrict__ tb,
    const short* __restrict__ Wob, float* __restrict__ out)
{
  constexpr int HC = 128, LDp = 132, NC = HD / HC;
  const int b  = blockIdx.z;
  const int s0 = blockIdx.y * 8, t0 = blockIdx.x * 16;

  __shared__ float sa[8][LDp];
  __shared__ float sb[16][LDp];

  const int tid = threadIdx.x, wave = tid >> 6, lane = tid & 63;
  const int lg = lane >> 4;       // k sub-group (0..3) / output t-quad
  const int ln = lane & 15;       // A-row t / B-col r

  f32x4 acc[2] = {};              // one per owned s-row, full-K accumulate

  const float* taB = ta + ((size_t)b * SQ + s0) * HD;
  const float* tbB = tb + ((size_t)b * SQ + t0) * HD;

  // staging assignment: sa row sr (0..7) col sq*4 ; sb rows rba, rba+8
  const int sr = tid >> 5, sq = tid & 31;
  const int rba = tid >> 5;        // 0..7 (row for first sb load)

  // prologue: chunk 0 -> regs
  float4 va  = *(const float4*)(taB + (size_t)sr * HD + sq * 4);
  float4 vb0 = *(const float4*)(tbB + (size_t)rba * HD + sq * 4);
  float4 vb1 = *(const float4*)(tbB + (size_t)(rba + 8) * HD + sq * 4);

  for (int c = 0; c < NC; ++c) {
    // write staged regs for chunk c
    *(float4*)&sa[sr][sq * 4]       = va;
    *(float4*)&sb[rba][sq * 4]      = vb0;
    *(float4*)&sb[rba + 8][sq * 4]  = vb1;
    __syncthreads();

    // issue next-chunk loads; latency hides under compute below
    if (c + 1 < NC) {
      va  = *(const float4*)(taB + (size_t)sr * HD + (c + 1) * HC + sq * 4);
      vb0 = *(const float4*)(tbB + (size_t)rba * HD + (c + 1) * HC + sq * 4);
      vb1 = *(const float4*)(tbB + (size_t)(rba + 8) * HD + (c + 1) * HC + sq * 4);
    }

    #pragma unroll
    for (int m = 0; m < 4; ++m) {
      const int kk = m * 32 + lg * 8;
      // B fragment from padded bf16 Wout (rows 7..15 are zeros)
      bf16x8 bfr = *(const bf16x8*)(Wob + (size_t)ln * HD + c * HC + kk);
      // tb values for this lane's t row (t = ln)
      float4 q0 = *(const float4*)&sb[ln][kk];
      float4 q1 = *(const float4*)&sb[ln][kk + 4];
      float bvv[8] = {q0.x,q0.y,q0.z,q0.w,q1.x,q1.y,q1.z,q1.w};

      #pragma unroll
      for (int si = 0; si < 2; ++si) {
        const float* ap = &sa[wave * 2 + si][kk];   // broadcast within 16-lane group
        float4 a0 = *(const float4*)ap;
        float4 a1 = *(const float4*)(ap + 4);
        float av[8] = {a0.x,a0.y,a0.z,a0.w,a1.x,a1.y,a1.z,a1.w};
        bf16x8 pa;
        #pragma unroll
        for (int j = 0; j < 8; ++j)
          pa[j] = f2bf(pair_tanh(av[j], bvv[j]));
        acc[si] = __builtin_amdgcn_mfma_f32_16x16x32_bf16(pa, bfr, acc[si], 0, 0, 0);
      }
    }
    __syncthreads();   // all reads of chunk c done (also drains c+1 reg loads)
  }

  // D layout: row(M=t) = lg*4+reg, col(N=r) = ln
  if (ln < RR) {
    #pragma unroll
    for (int si = 0; si < 2; ++si) {
      int s = s0 + wave * 2 + si;
      float* op = out + (((size_t)b * SQ + s) * SQ + t0 + lg * 4) * RR + ln;
      op[0]      = acc[si][0];
      op[RR]     = acc[si][1];
      op[2 * RR] = acc[si][2];
      op[3 * RR] = acc[si][3];
    }
  }
}

extern "C" void kernel_launch(void* const* d_in, const int* in_sizes, int n_in,
                              void* d_out, int out_size, void* d_ws, size_t ws_size,
                              hipStream_t stream) {
  (void)in_sizes; (void)n_in; (void)out_size;
  const float* X    = (const float*)d_in[0];
  const float* Wsrc = (const float*)d_in[1];
  const float* bsrc = (const float*)d_in[2];
  const float* Wtgt = (const float*)d_in[3];
  const float* btgt = (const float*)d_in[4];
  const float* Wout = (const float*)d_in[5];
  float* out = (float*)d_out;

  float* taF = (float*)d_ws;                       // [1024,768] f32
  float* tbF = taF + (size_t)NB * SQ * HD;         // [1024,768] f32
  const size_t base = (size_t)2 * NB * SQ * HD * sizeof(float);
  short* Xb  = (short*)((char*)d_ws + base);
  short* Wsb = Xb + (size_t)NB * SQ * HD;
  short* Wtb = Wsb + (size_t)HD * HD;
  short* Wob = Wtb + (size_t)HD * HD;
  const size_t need = base +
      ((size_t)NB * SQ * HD + 2 * (size_t)HD * HD + (size_t)16 * HD) * sizeof(short);

  const short* WobUse;
  if (ws_size >= need) {
    const int total_oct = NB*SQ*HD/8 + 2*(HD*HD/8) + 16*HD/8;
    cvt_kernel<<<(total_oct + 255) / 256, 256, 0, stream>>>(
        X, Wsrc, Wtgt, Wout, Xb, Wsb, Wtb, Wob);
    stage1_lds<<<dim3(16, 12, 2), 256, 0, stream>>>(Xb, Wsb, bsrc, Wtb, btgt, taF, tbF);
    WobUse = Wob;
  } else {
    short* WobF = (short*)((char*)d_ws + base);   // only padded Wout bf16 after ta/tb
    cvt_wout<<<6, 256, 0, stream>>>(Wout, WobF);
    stage1_mfma<<<dim3(16, 12, 2), 256, 0, stream>>>(X, Wsrc, bsrc, Wtgt, btgt, taF, tbF);
    WobUse = WobF;
  }
  stage2_mfma<<<dim3(SQ / 16, SQ / 8, NB), 256, 0, stream>>>(taF, tbF, WobUse, out);
}

// Round 11
// 114.831 us; speedup vs baseline: 1.0523x; 1.0011x over previous
//
#include <hip/hip_runtime.h>
#include <hip/hip_bf16.h>

#define HD 768
#define SQ 256
#define NB 4
#define RR 7

typedef short bf16x8 __attribute__((ext_vector_type(8)));
typedef float f32x4  __attribute__((ext_vector_type(4)));

__device__ __forceinline__ float fast_tanh(float x) {
  // tanh(x) = 1 - 2/(e^{2x}+1); stable for large |x|
  float e = __expf(2.0f * x);
  return 1.0f - 2.0f / (e + 1.0f);
}

__device__ __forceinline__ float pair_tanh(float a, float b) {
  // tanh(u+v) = (a+b)/(1+ab) with a=tanh u, b=tanh v (exact identity)
  return (a + b) * __builtin_amdgcn_rcpf(fmaf(a, b, 1.0f));
}

__device__ __forceinline__ short f2bf(float x) {
  return (short)__builtin_bit_cast(unsigned short, __float2bfloat16(x));
}

__device__ __forceinline__ void gl_lds16(const void* g, void* l) {
  // async 16B/lane global->LDS; LDS dest = wave-uniform base + lane*16
  __builtin_amdgcn_global_load_lds(
      (const __attribute__((address_space(1))) void*)g,
      (__attribute__((address_space(3))) void*)l, 16, 0, 0);
}

// ------- convert: f32 -> bf16 for X, Wsrc, Wtgt; Wout padded to 16 rows -------
__global__ __launch_bounds__(256) void cvt_kernel(
    const float* __restrict__ X, const float* __restrict__ Ws,
    const float* __restrict__ Wt, const float* __restrict__ Wo,
    short* __restrict__ Xb, short* __restrict__ Wsb,
    short* __restrict__ Wtb, short* __restrict__ Wob)
{
  const int NX = NB * SQ * HD / 8;   // 98304 octets
  const int NW = HD * HD / 8;        // 73728 octets
  const int NO = 16 * HD / 8;        // 1536 octets (padded rows)
  int i = blockIdx.x * 256 + threadIdx.x;
  const float* src; short* dst;
  if (i < NX)               { src = X;  dst = Xb; }
  else if (i < NX + NW)     { src = Ws; dst = Wsb; i -= NX; }
  else if (i < NX + 2 * NW) { src = Wt; dst = Wtb; i -= NX + NW; }
  else if (i < NX + 2 * NW + NO) {
    i -= NX + 2 * NW;
    int row = i / (HD / 8);
    bf16x8 r = {};
    if (row < RR) {
      float4 a = *(const float4*)(Wo + (size_t)i * 8);
      float4 b = *(const float4*)(Wo + (size_t)i * 8 + 4);
      r[0] = f2bf(a.x); r[1] = f2bf(a.y); r[2] = f2bf(a.z); r[3] = f2bf(a.w);
      r[4] = f2bf(b.x); r[5] = f2bf(b.y); r[6] = f2bf(b.z); r[7] = f2bf(b.w);
    }
    *(bf16x8*)(Wob + (size_t)i * 8) = r;
    return;
  } else return;
  float4 a = *(const float4*)(src + (size_t)i * 8);
  float4 b = *(const float4*)(src + (size_t)i * 8 + 4);
  bf16x8 r;
  r[0] = f2bf(a.x); r[1] = f2bf(a.y); r[2] = f2bf(a.z); r[3] = f2bf(a.w);
  r[4] = f2bf(b.x); r[5] = f2bf(b.y); r[6] = f2bf(b.z); r[7] = f2bf(b.w);
  *(bf16x8*)(dst + (size_t)i * 8) = r;
}

// small fallback converter: Wout only (padded to 16 rows)
__global__ __launch_bounds__(256) void cvt_wout(
    const float* __restrict__ Wo, short* __restrict__ Wob)
{
  const int NO = 16 * HD / 8;
  int i = blockIdx.x * 256 + threadIdx.x;
  if (i >= NO) return;
  int row = i / (HD / 8);
  bf16x8 r = {};
  if (row < RR) {
    float4 a = *(const float4*)(Wo + (size_t)i * 8);
    float4 b = *(const float4*)(Wo + (size_t)i * 8 + 4);
    r[0] = f2bf(a.x); r[1] = f2bf(a.y); r[2] = f2bf(a.z); r[3] = f2bf(a.w);
    r[4] = f2bf(b.x); r[5] = f2bf(b.y); r[6] = f2bf(b.z); r[7] = f2bf(b.w);
  }
  *(bf16x8*)(Wob + (size_t)i * 8) = r;
}

// -------- Stage 1: ta/tb = tanh(Xb @ Wb^T + bias); BM=32 tile, 768 blocks --------
__global__ __launch_bounds__(256) void stage1_lds(
    const short* __restrict__ Xb,
    const short* __restrict__ Wsb, const float* __restrict__ bsrc,
    const short* __restrict__ Wtb, const float* __restrict__ btgt,
    float* __restrict__ ta, float* __restrict__ tb)
{
  constexpr int BK = 64, BM = 32, BN = 64;
  const short* W  = blockIdx.z ? Wtb : Wsb;
  const float* bv = blockIdx.z ? btgt : bsrc;
  float* outp     = blockIdx.z ? tb : ta;
  const int row0 = blockIdx.x * BM, col0 = blockIdx.y * BN;

  // double-buffered; content granule(r,g) = global (r, g^(r&7))
  __shared__ short As[2][BM * BK];   // 4 KB per buf
  __shared__ short Bs[2][BN * BK];   // 8 KB per buf

  const int tid = threadIdx.x, wave = tid >> 6, lane = tid & 63;
  const int ln = lane & 15, lg = lane >> 4;
  const int wm = (wave >> 1) * 16, wn = (wave & 1) * 32;

  f32x4 acc[2] = {};

  // A staging: 256 granules (32 rows x 8/row), one per thread
  const int ra = tid >> 3, ga = tid & 7;
  const size_t xoff = (size_t)(row0 + ra) * HD + ((ga ^ (ra & 7)) * 8);
  // B staging: 512 granules (64 rows x 8/row), threads t and t+256
  const int rb0 = tid >> 3, gb0 = tid & 7;
  const int rb1 = (tid + 256) >> 3, gb1 = tid & 7;
  const size_t wof0 = (size_t)(col0 + rb0) * HD + ((gb0 ^ (rb0 & 7)) * 8);
  const size_t wof1 = (size_t)(col0 + rb1) * HD + ((gb1 ^ (rb1 & 7)) * 8);
  short* const laA  = (short*)As + (size_t)(wave * 64) * 8;
  short* const laB0 = (short*)Bs + (size_t)(wave * 64) * 8;
  short* const laB1 = (short*)Bs + (size_t)(256 + wave * 64) * 8;
  constexpr int BUFA = BM * BK, BUFB = BN * BK;

  // prologue: stage tile 0 into buf 0
  gl_lds16(Xb + xoff, laA);
  gl_lds16(W + wof0, laB0);
  gl_lds16(W + wof1, laB1);

  int cur = 0;
  for (int k0 = 0; k0 < HD; k0 += BK) {
    __syncthreads();   // drains vmcnt: buf[cur] ready; prev reads of buf[cur^1] done
    if (k0 + BK < HD) {  // issue next tile into buf[cur^1]; flies under compute
      gl_lds16(Xb + xoff + k0 + BK, laA + (cur ^ 1) * BUFA);
      gl_lds16(W + wof0 + k0 + BK, laB0 + (cur ^ 1) * BUFB);
      gl_lds16(W + wof1 + k0 + BK, laB1 + (cur ^ 1) * BUFB);
    }
    const short* Ac = (const short*)As + cur * BUFA;
    const short* Bc = (const short*)Bs + cur * BUFB;

    #pragma unroll
    for (int kkb = 0; kkb < 2; ++kkb) {
      const int q = kkb * 4 + lg;
      const int ar = wm + ln;
      bf16x8 af = *(const bf16x8*)&Ac[ar * BK + ((q ^ (ar & 7)) * 8)];
      bf16x8 bw[2];
      #pragma unroll
      for (int i = 0; i < 2; ++i) {
        int br = wn + i * 16 + ln;
        bw[i] = *(const bf16x8*)&Bc[br * BK + ((q ^ (br & 7)) * 8)];
      }
      #pragma unroll
      for (int i = 0; i < 2; ++i)
        acc[i] = __builtin_amdgcn_mfma_f32_16x16x32_bf16(af, bw[i], acc[i], 0, 0, 0);
    }
    cur ^= 1;
  }

  #pragma unroll
  for (int j = 0; j < 2; ++j) {
    int n = col0 + wn + j * 16 + ln;
    float bb = bv[n];
    #pragma unroll
    for (int r = 0; r < 4; ++r) {
      int m = row0 + wm + lg * 4 + r;
      outp[(size_t)m * HD + n] = fast_tanh(acc[j][r] + bb);
    }
  }
}

// -------- Stage 1 fallback (in-kernel convert; used if ws too small) --------
__global__ __launch_bounds__(256) void stage1_mfma(
    const float* __restrict__ X,
    const float* __restrict__ Wsrc, const float* __restrict__ bsrc,
    const float* __restrict__ Wtgt, const float* __restrict__ btgt,
    float* __restrict__ ta, float* __restrict__ tb)
{
  constexpr int BK = 64;
  const float* W  = blockIdx.z ? Wtgt : Wsrc;
  const float* bv = blockIdx.z ? btgt : bsrc;
  float* outp     = blockIdx.z ? tb : ta;
  const int row0 = blockIdx.x * 64, col0 = blockIdx.y * 64;

  __shared__ short As[64 * BK];
  __shared__ short Bs[64 * BK];

  const int tid  = threadIdx.x;
  const int wave = tid >> 6, lane = tid & 63;
  const int wm = (wave >> 1) * 32, wn = (wave & 1) * 32;
  f32x4 acc[2][2] = {};
  const int sr = tid >> 2, sq = tid & 3;

  for (int k0 = 0; k0 < HD; k0 += BK) {
    const float* xa = X + (size_t)(row0 + sr) * HD + k0 + sq * 16;
    const float* xw = W + (size_t)(col0 + sr) * HD + k0 + sq * 16;
    float4 a0 = *(const float4*)(xa + 0), a1 = *(const float4*)(xa + 4);
    float4 a2 = *(const float4*)(xa + 8), a3 = *(const float4*)(xa + 12);
    float4 w0 = *(const float4*)(xw + 0), w1 = *(const float4*)(xw + 4);
    float4 w2 = *(const float4*)(xw + 8), w3 = *(const float4*)(xw + 12);
    __syncthreads();
    bf16x8 p;
    p[0]=f2bf(a0.x);p[1]=f2bf(a0.y);p[2]=f2bf(a0.z);p[3]=f2bf(a0.w);
    p[4]=f2bf(a1.x);p[5]=f2bf(a1.y);p[6]=f2bf(a1.z);p[7]=f2bf(a1.w);
    *(bf16x8*)&As[sr * BK + (((sq * 2 + 0) ^ (sr & 7)) * 8)] = p;
    p[0]=f2bf(a2.x);p[1]=f2bf(a2.y);p[2]=f2bf(a2.z);p[3]=f2bf(a2.w);
    p[4]=f2bf(a3.x);p[5]=f2bf(a3.y);p[6]=f2bf(a3.z);p[7]=f2bf(a3.w);
    *(bf16x8*)&As[sr * BK + (((sq * 2 + 1) ^ (sr & 7)) * 8)] = p;
    p[0]=f2bf(w0.x);p[1]=f2bf(w0.y);p[2]=f2bf(w0.z);p[3]=f2bf(w0.w);
    p[4]=f2bf(w1.x);p[5]=f2bf(w1.y);p[6]=f2bf(w1.z);p[7]=f2bf(w1.w);
    *(bf16x8*)&Bs[sr * BK + (((sq * 2 + 0) ^ (sr & 7)) * 8)] = p;
    p[0]=f2bf(w2.x);p[1]=f2bf(w2.y);p[2]=f2bf(w2.z);p[3]=f2bf(w2.w);
    p[4]=f2bf(w3.x);p[5]=f2bf(w3.y);p[6]=f2bf(w3.z);p[7]=f2bf(w3.w);
    *(bf16x8*)&Bs[sr * BK + (((sq * 2 + 1) ^ (sr & 7)) * 8)] = p;
    __syncthreads();

    #pragma unroll
    for (int kkb = 0; kkb < 2; ++kkb) {
      bf16x8 af[2], bw[2];
      const int q = kkb * 4 + (lane >> 4);
      #pragma unroll
      for (int i = 0; i < 2; ++i) {
        int ar = wm + i * 16 + (lane & 15);
        af[i] = *(const bf16x8*)&As[ar * BK + ((q ^ (ar & 7)) * 8)];
        int br = wn + i * 16 + (lane & 15);
        bw[i] = *(const bf16x8*)&Bs[br * BK + ((q ^ (br & 7)) * 8)];
      }
      #pragma unroll
      for (int i = 0; i < 2; ++i)
        #pragma unroll
        for (int j = 0; j < 2; ++j)
          acc[i][j] = __builtin_amdgcn_mfma_f32_16x16x32_bf16(af[i], bw[j], acc[i][j], 0, 0, 0);
    }
  }

  #pragma unroll
  for (int j = 0; j < 2; ++j) {
    int n = col0 + wn + j * 16 + (lane & 15);
    float bb = bv[n];
    #pragma unroll
    for (int i = 0; i < 2; ++i)
      #pragma unroll
      for (int r = 0; r < 4; ++r) {
        int m = row0 + wm + i * 16 + (lane >> 4) * 4 + r;
        outp[(size_t)m * HD + n] = fast_tanh(acc[i][j][r] + bb);
      }
  }
}

// ---- Stage 2: out[b,s,t,r] via MFMA; 8s x 16t tile, wave owns 2 s-rows.
//      Pipelined: next-chunk ta/tb -> regs AND next-chunk Wout frags -> regs
//      both issued right after the barrier, consumed a full chunk later. ----
__global__ __launch_bounds__(256, 5) void stage2_mfma(
    const float* __restrict__ ta, const float* __restrict__ tb,
    const short* __restrict__ Wob, float* __restrict__ out)
{
  constexpr int HC = 128, LDp = 132, NC = HD / HC;
  const int b  = blockIdx.z;
  const int s0 = blockIdx.y * 8, t0 = blockIdx.x * 16;

  __shared__ float sa[8][LDp];
  __shared__ float sb[16][LDp];

  const int tid = threadIdx.x, wave = tid >> 6, lane = tid & 63;
  const int lg = lane >> 4;       // k sub-group (0..3) / output t-quad
  const int ln = lane & 15;       // A-row t / B-col r

  f32x4 acc[2] = {};              // one per owned s-row, full-K accumulate

  const float* taB = ta + ((size_t)b * SQ + s0) * HD;
  const float* tbB = tb + ((size_t)b * SQ + t0) * HD;
  const short* wrow = Wob + (size_t)ln * HD + lg * 8;   // this lane's Wout row base

  // staging assignment: sa row sr (0..7) col sq*4 ; sb rows rba, rba+8
  const int sr = tid >> 5, sq = tid & 31;
  const int rba = tid >> 5;

  // prologue: chunk 0 staged data -> regs, chunk 0 Wout frags -> regs
  float4 va  = *(const float4*)(taB + (size_t)sr * HD + sq * 4);
  float4 vb0 = *(const float4*)(tbB + (size_t)rba * HD + sq * 4);
  float4 vb1 = *(const float4*)(tbB + (size_t)(rba + 8) * HD + sq * 4);
  bf16x8 bfr[4], bfrN[4];
  #pragma unroll
  for (int m = 0; m < 4; ++m)
    bfr[m] = *(const bf16x8*)(wrow + m * 32);

  #pragma unroll
  for (int c = 0; c < NC; ++c) {
    // write staged regs for chunk c
    *(float4*)&sa[sr][sq * 4]       = va;
    *(float4*)&sb[rba][sq * 4]      = vb0;
    *(float4*)&sb[rba + 8][sq * 4]  = vb1;
    __syncthreads();

    // issue next-chunk loads; latency hides under the compute below
    if (c + 1 < NC) {
      va  = *(const float4*)(taB + (size_t)sr * HD + (c + 1) * HC + sq * 4);
      vb0 = *(const float4*)(tbB + (size_t)rba * HD + (c + 1) * HC + sq * 4);
      vb1 = *(const float4*)(tbB + (size_t)(rba + 8) * HD + (c + 1) * HC + sq * 4);
      #pragma unroll
      for (int m = 0; m < 4; ++m)
        bfrN[m] = *(const bf16x8*)(wrow + (c + 1) * HC + m * 32);
    }

    #pragma unroll
    for (int m = 0; m < 4; ++m) {
      const int kk = m * 32 + lg * 8;
      // tb values for this lane's t row (t = ln)
      float4 q0 = *(const float4*)&sb[ln][kk];
      float4 q1 = *(const float4*)&sb[ln][kk + 4];
      float bvv[8] = {q0.x,q0.y,q0.z,q0.w,q1.x,q1.y,q1.z,q1.w};

      #pragma unroll
      for (int si = 0; si < 2; ++si) {
        const float* ap = &sa[wave * 2 + si][kk];   // broadcast within 16-lane group
        float4 a0 = *(const float4*)ap;
        float4 a1 = *(const float4*)(ap + 4);
        float av[8] = {a0.x,a0.y,a0.z,a0.w,a1.x,a1.y,a1.z,a1.w};
        bf16x8 pa;
        #pragma unroll
        for (int j = 0; j < 8; ++j)
          pa[j] = f2bf(pair_tanh(av[j], bvv[j]));
        acc[si] = __builtin_amdgcn_mfma_f32_16x16x32_bf16(pa, bfr[m], acc[si], 0, 0, 0);
      }
    }
    __syncthreads();   // all reads of chunk c done (also orders next LDS writes)
    if (c + 1 < NC) {
      #pragma unroll
      for (int m = 0; m < 4; ++m)
        bfr[m] = bfrN[m];   // renamed away by the full unroll
    }
  }

  // D layout: row(M=t) = lg*4+reg, col(N=r) = ln
  if (ln < RR) {
    #pragma unroll
    for (int si = 0; si < 2; ++si) {
      int s = s0 + wave * 2 + si;
      float* op = out + (((size_t)b * SQ + s) * SQ + t0 + lg * 4) * RR + ln;
      op[0]      = acc[si][0];
      op[RR]     = acc[si][1];
      op[2 * RR] = acc[si][2];
      op[3 * RR] = acc[si][3];
    }
  }
}

extern "C" void kernel_launch(void* const* d_in, const int* in_sizes, int n_in,
                              void* d_out, int out_size, void* d_ws, size_t ws_size,
                              hipStream_t stream) {
  (void)in_sizes; (void)n_in; (void)out_size;
  const float* X    = (const float*)d_in[0];
  const float* Wsrc = (const float*)d_in[1];
  const float* bsrc = (const float*)d_in[2];
  const float* Wtgt = (const float*)d_in[3];
  const float* btgt = (const float*)d_in[4];
  const float* Wout = (const float*)d_in[5];
  float* out = (float*)d_out;

  float* taF = (float*)d_ws;                       // [1024,768] f32
  float* tbF = taF + (size_t)NB * SQ * HD;         // [1024,768] f32
  const size_t base = (size_t)2 * NB * SQ * HD * sizeof(float);
  short* Xb  = (short*)((char*)d_ws + base);
  short* Wsb = Xb + (size_t)NB * SQ * HD;
  short* Wtb = Wsb + (size_t)HD * HD;
  short* Wob = Wtb + (size_t)HD * HD;
  const size_t need = base +
      ((size_t)NB * SQ * HD + 2 * (size_t)HD * HD + (size_t)16 * HD) * sizeof(short);

  const short* WobUse;
  if (ws_size >= need) {
    const int total_oct = NB*SQ*HD/8 + 2*(HD*HD/8) + 16*HD/8;
    cvt_kernel<<<(total_oct + 255) / 256, 256, 0, stream>>>(
        X, Wsrc, Wtgt, Wout, Xb, Wsb, Wtb, Wob);
    stage1_lds<<<dim3(32, 12, 2), 256, 0, stream>>>(Xb, Wsb, bsrc, Wtb, btgt, taF, tbF);
    WobUse = Wob;
  } else {
    short* WobF = (short*)((char*)d_ws + base);   // only padded Wout bf16 after ta/tb
    cvt_wout<<<6, 256, 0, stream>>>(Wout, WobF);
    stage1_mfma<<<dim3(16, 12, 2), 256, 0, stream>>>(X, Wsrc, bsrc, Wtgt, btgt, taF, tbF);
    WobUse = WobF;
  }
  stage2_mfma<<<dim3(SQ / 16, SQ / 8, NB), 256, 0, stream>>>(taF, tbF, WobUse, out);
}